// Round 5
// baseline (251.975 us; speedup 1.0000x reference)
//
#include <hip/hip_runtime.h>
#include <cstddef>
#include <cstdint>

// LocalAttention MI355X round 5: 4 dispatches.
//   cvt_all:    w_qkv, w_out, x  fp32 -> bf16 (one grid-stride kernel)
//   gemm_qkv:   xb @ w_qkv^T, MFMA 16x16x32, global_load_lds(16B) staging,
//               XCD-swizzled grid 1536 -> bf16 Q/K/V head-major [bh][p][64]
//   attn_fused: 16x16 pixel tile; 20x20 K-halo in LDS -> 25-dot softmax in
//               regs -> barrier -> V-halo reuses same LDS -> weighted sum
//               -> AO bf16 [b][p][512]  (AO is its OWN buffer: aliasing Q
//               would race now that QK and PV share one kernel)
//   gemm_out:   AO @ w_out^T + b_out -> fp32 out
// ws use: 86 MB of the 256 MiB workspace.

namespace {

typedef short s16x8 __attribute__((ext_vector_type(8)));
typedef unsigned short u16x8 __attribute__((ext_vector_type(8)));
typedef float f32x4 __attribute__((ext_vector_type(4)));

constexpr int kHeads = 8;
constexpr int kN = 4096;          // pixels per image
constexpr float kScale = 0.125f;  // 64^-0.5

__device__ inline float b2f(unsigned short u) {
  return __uint_as_float((unsigned)u << 16);
}
__device__ inline unsigned short f2b(float x) {
  unsigned u = __float_as_uint(x);  // RNE
  return (unsigned short)((u + 0x7fffu + ((u >> 16) & 1u)) >> 16);
}

// async global->LDS, 16 B per lane; LDS dest = wave-uniform base + lane*16
__device__ __forceinline__ void g2l16(const unsigned short* g,
                                      unsigned short* l) {
  __builtin_amdgcn_global_load_lds(
      (const __attribute__((address_space(1))) void*)g,
      (__attribute__((address_space(3))) void*)l, 16, 0, 0);
}

// ---------------- fp32 -> bf16 for all three tensors -------------------------
// chunk = 8 floats. w_qkv: 98304 chunks, w_out: 32768, x: 1048576.
__global__ __launch_bounds__(256) void cvt_all(
    const float* __restrict__ wq, const float* __restrict__ wo,
    const float* __restrict__ x, unsigned short* __restrict__ wqb,
    unsigned short* __restrict__ wob, unsigned short* __restrict__ xb) {
  const int i = blockIdx.x * 256 + threadIdx.x;  // 0..1179647
  const float* src;
  unsigned short* dst;
  int off;
  if (i < 98304) {
    src = wq; dst = wqb; off = i;
  } else if (i < 131072) {
    src = wo; dst = wob; off = i - 98304;
  } else {
    src = x; dst = xb; off = i - 131072;
  }
  const float4 a = ((const float4*)src)[off * 2];
  const float4 b = ((const float4*)src)[off * 2 + 1];
  u16x8 o;
  o[0] = f2b(a.x); o[1] = f2b(a.y); o[2] = f2b(a.z); o[3] = f2b(a.w);
  o[4] = f2b(b.x); o[5] = f2b(b.y); o[6] = f2b(b.z); o[7] = f2b(b.w);
  *(u16x8*)(dst + (size_t)off * 8) = o;
}

// ---------------- MFMA GEMM core: 128x128 tile, K=512, BK=32 ----------------
// A,W bf16 row-major k-contiguous. LDS unpadded [128][32]. 4 waves, each 64x64.
__device__ __forceinline__ void mfma_512(const unsigned short* __restrict__ A,
                                         const unsigned short* __restrict__ W,
                                         int m0, int n0, int tid,
                                         unsigned short* As, unsigned short* Bs,
                                         f32x4 (&acc)[4][4]) {
  const int lane = tid & 63;
  const int wv = tid >> 6;
  const int wm = wv & 1, wn = wv >> 1;
  const int rr = lane >> 2;       // row within 16-row group
  const int cc = (lane & 3) * 8;  // k elem offset
#pragma unroll
  for (int i = 0; i < 4; ++i)
#pragma unroll
    for (int j = 0; j < 4; ++j) acc[i][j] = f32x4{0.f, 0.f, 0.f, 0.f};

  for (int k0 = 0; k0 < 512; k0 += 32) {
#pragma unroll
    for (int it = 0; it < 2; ++it) {
      const int grp = wv * 2 + it;  // 0..7
      const int row = grp * 16 + rr;
      g2l16(A + (size_t)(m0 + row) * 512 + k0 + cc, As + grp * 512);
      g2l16(W + (size_t)(n0 + row) * 512 + k0 + cc, Bs + grp * 512);
    }
    __syncthreads();
    s16x8 af[4], bf[4];
#pragma unroll
    for (int i = 0; i < 4; ++i) {
      af[i] = *(const s16x8*)&As[(wm * 64 + i * 16 + (lane & 15)) * 32 +
                                 (lane >> 4) * 8];
      bf[i] = *(const s16x8*)&Bs[(wn * 64 + i * 16 + (lane & 15)) * 32 +
                                 (lane >> 4) * 8];
    }
#pragma unroll
    for (int i = 0; i < 4; ++i)
#pragma unroll
      for (int j = 0; j < 4; ++j)
        acc[i][j] = __builtin_amdgcn_mfma_f32_16x16x32_bf16(af[i], bf[j],
                                                            acc[i][j], 0, 0, 0);
    __syncthreads();
  }
}

// ---------------- QKV projection GEMM, full M=16384 --------------------------
// grid 1536: xcd=id&7 owns row-slabs [xcd*16, xcd*16+16) x 12 col-tiles
__global__ __launch_bounds__(256, 4) void gemm_qkv(
    const unsigned short* __restrict__ A, const unsigned short* __restrict__ W,
    unsigned short* __restrict__ Qb, unsigned short* __restrict__ Kb,
    unsigned short* __restrict__ Vb) {
  __shared__ unsigned short As[4096], Bs[4096];
  const int tid = threadIdx.x;
  const int id = blockIdx.x;
  const int xcd = id & 7;
  const int j = id >> 3;            // 0..191
  const int by = xcd * 16 + j / 12; // 0..127
  const int bx = j % 12;
  f32x4 acc[4][4];
  mfma_512(A, W, by * 128, bx * 128, tid, As, Bs, acc);

  const int lane = tid & 63;
  const int wv = tid >> 6;
  const int wm = wv & 1, wn = wv >> 1;
  const int cn = bx * 128 + wn * 64;  // 64-aligned => head/qkv wave-uniform
  unsigned short* dst = (cn < 512) ? Qb : (cn < 1024 ? Kb : Vb);
  const int head = (cn >> 6) & 7;
  const int colb = lane & 15;
#pragma unroll
  for (int mi = 0; mi < 4; ++mi) {
#pragma unroll
    for (int r = 0; r < 4; ++r) {
      const int m = by * 128 + wm * 64 + mi * 16 + (lane >> 4) * 4 + r;
      const int b = m >> 12;
      const int p = m & 4095;
      unsigned short* o =
          dst + ((size_t)(b * kHeads + head) * kN + p) * 64 + colb;
#pragma unroll
      for (int ni = 0; ni < 4; ++ni) o[ni * 16] = f2b(acc[mi][ni][r]);
    }
  }
}

// ---------------- out-projection GEMM ----------------------------------------
// grid 512: xcd=id&7 owns row-slabs [xcd*16, xcd*16+16) x 4 col-tiles
__global__ __launch_bounds__(256, 4) void gemm_out(
    const unsigned short* __restrict__ A, const unsigned short* __restrict__ W,
    const float* __restrict__ bias, float* __restrict__ out) {
  __shared__ unsigned short As[4096], Bs[4096];
  const int tid = threadIdx.x;
  const int id = blockIdx.x;
  const int xcd = id & 7;
  const int j = id >> 3;               // 0..63
  const int by = xcd * 16 + (j >> 2);  // 0..127
  const int bx = j & 3;
  f32x4 acc[4][4];
  mfma_512(A, W, by * 128, bx * 128, tid, As, Bs, acc);

  const int lane = tid & 63;
  const int wv = tid >> 6;
  const int wm = wv & 1, wn = wv >> 1;
  float bvr[4];
#pragma unroll
  for (int ni = 0; ni < 4; ++ni)
    bvr[ni] = bias[bx * 128 + wn * 64 + ni * 16 + (lane & 15)];
#pragma unroll
  for (int mi = 0; mi < 4; ++mi) {
#pragma unroll
    for (int r = 0; r < 4; ++r) {
      const int m = by * 128 + wm * 64 + mi * 16 + (lane >> 4) * 4 + r;
      float* o = out + (size_t)m * 512 + bx * 128 + wn * 64 + (lane & 15);
#pragma unroll
      for (int ni = 0; ni < 4; ++ni) o[ni * 16] = acc[mi][ni][r] + bvr[ni];
    }
  }
}

// ---------------- fused local attention --------------------------------------
// Block: 16x16 pixel tile of one (b,h). One 57.6 KB LDS halo buffer, used
// first for K (dots+softmax in regs), then re-filled with V (weighted sum).
// OOB halo rows are zero => logit 0 in softmax, zero V (zero-pad reference).
__global__ __launch_bounds__(256) void attn_fused(
    const unsigned short* __restrict__ Q, const unsigned short* __restrict__ K,
    const unsigned short* __restrict__ V, unsigned short* __restrict__ AO) {
  __shared__ unsigned short H[400 * 72];  // 57.6 KB
  const int tid = threadIdx.x;
  const int bh = blockIdx.y;
  const int tile = blockIdx.x;
  const int ty0 = (tile >> 2) * 16, tx0 = (tile & 3) * 16;
  const size_t base = (size_t)bh * kN;
  const int pyl = tid >> 4, pxl = tid & 15;
  const int p = (ty0 + pyl) * 64 + tx0 + pxl;

  // ---- phase 1: K halo ----
  for (int i = tid; i < 3200; i += 256) {
    const int r = i >> 3, c = i & 7;
    const int gy = ty0 - 2 + r / 20;
    const int gx = tx0 - 2 + r % 20;
    u16x8 v = {};
    if ((unsigned)gy < 64u && (unsigned)gx < 64u)
      v = *(const u16x8*)(K + (base + gy * 64 + gx) * 64 + c * 8);
    *(u16x8*)&H[r * 72 + c * 8] = v;
  }

  float q[64];
  {
    const unsigned short* qp = Q + (base + p) * 64;
#pragma unroll
    for (int c = 0; c < 8; ++c) {
      const u16x8 v = *(const u16x8*)(qp + c * 8);
#pragma unroll
      for (int jj = 0; jj < 8; ++jj) q[c * 8 + jj] = b2f(v[jj]);
    }
  }
  __syncthreads();

  float dots[25];
  float mx = -1e30f;
#pragma unroll
  for (int fy = 0; fy < 5; ++fy) {
#pragma unroll
    for (int fx = 0; fx < 5; ++fx) {
      const unsigned short* kr = &H[((pyl + fy) * 20 + pxl + fx) * 72];
      float d = 0.f;
#pragma unroll
      for (int c = 0; c < 8; ++c) {
        const u16x8 kv = *(const u16x8*)(kr + c * 8);
#pragma unroll
        for (int jj = 0; jj < 8; ++jj) d = fmaf(q[c * 8 + jj], b2f(kv[jj]), d);
      }
      d *= kScale;
      dots[fy * 5 + fx] = d;
      mx = fmaxf(mx, d);
    }
  }
  float sum = 0.f;
#pragma unroll
  for (int f = 0; f < 25; ++f) {
    dots[f] = __expf(dots[f] - mx);
    sum += dots[f];
  }
  const float inv = 1.f / sum;
#pragma unroll
  for (int f = 0; f < 25; ++f) dots[f] *= inv;

  // ---- phase 2: V halo reuses H ----
  __syncthreads();  // everyone done reading K halo
  for (int i = tid; i < 3200; i += 256) {
    const int r = i >> 3, c = i & 7;
    const int gy = ty0 - 2 + r / 20;
    const int gx = tx0 - 2 + r % 20;
    u16x8 v = {};
    if ((unsigned)gy < 64u && (unsigned)gx < 64u)
      v = *(const u16x8*)(V + (base + gy * 64 + gx) * 64 + c * 8);
    *(u16x8*)&H[r * 72 + c * 8] = v;
  }
  __syncthreads();

  float o[64];
#pragma unroll
  for (int jj = 0; jj < 64; ++jj) o[jj] = 0.f;
#pragma unroll
  for (int fy = 0; fy < 5; ++fy) {
#pragma unroll
    for (int fx = 0; fx < 5; ++fx) {
      const unsigned short* vr = &H[((pyl + fy) * 20 + pxl + fx) * 72];
      const float wf = dots[fy * 5 + fx];
#pragma unroll
      for (int c = 0; c < 8; ++c) {
        const u16x8 vv = *(const u16x8*)(vr + c * 8);
#pragma unroll
        for (int jj = 0; jj < 8; ++jj)
          o[c * 8 + jj] = fmaf(wf, b2f(vv[jj]), o[c * 8 + jj]);
      }
    }
  }

  const int b = bh >> 3, h = bh & 7;
  unsigned short* op = AO + ((size_t)(b * kN + p)) * 512 + h * 64;
#pragma unroll
  for (int c = 0; c < 8; ++c) {
    u16x8 pk;
#pragma unroll
    for (int jj = 0; jj < 8; ++jj) pk[jj] = f2b(o[c * 8 + jj]);
    *(u16x8*)(op + c * 8) = pk;
  }
}

}  // namespace

extern "C" void kernel_launch(void* const* d_in, const int* in_sizes, int n_in,
                              void* d_out, int out_size, void* d_ws,
                              size_t ws_size, hipStream_t stream) {
  (void)in_sizes; (void)n_in; (void)out_size; (void)ws_size;
  const float* x = (const float*)d_in[0];      // [4,4096,512]
  const float* w_qkv = (const float*)d_in[1];  // [1536,512]
  const float* w_out = (const float*)d_in[2];  // [512,512]
  const float* b_out = (const float*)d_in[3];  // [512]
  float* out = (float*)d_out;                  // [4,4096,512] fp32

  unsigned short* ws0 = (unsigned short*)d_ws;
  unsigned short* wqkvb = ws0;              //   786,432
  unsigned short* woutb = ws0 + 786432;     //   262,144
  unsigned short* xb = ws0 + 1048576;       // 8,388,608
  unsigned short* Qb = ws0 + 9437184;       // 8,388,608
  unsigned short* Kb = ws0 + 17825792;      // 8,388,608
  unsigned short* Vb = ws0 + 26214400;      // 8,388,608
  unsigned short* AO = ws0 + 34603008;      // 8,388,608 -> 86 MB total

  cvt_all<<<4608, 256, 0, stream>>>(w_qkv, w_out, x, wqkvb, woutb, xb);
  gemm_qkv<<<1536, 256, 0, stream>>>(xb, wqkvb, Qb, Kb, Vb);
  attn_fused<<<dim3(16, 32), 256, 0, stream>>>(Qb, Kb, Vb, AO);
  gemm_out<<<512, 256, 0, stream>>>(AO, woutb, b_out, out);
}

// Round 6
// 178.063 us; speedup vs baseline: 1.4151x; 1.4151x over previous
//
#include <hip/hip_runtime.h>
#include <cstddef>
#include <cstdint>

// LocalAttention MI355X round 6: 4 dispatches.
//   cvt_all:     w_qkv, w_out, x  fp32 -> bf16 (one grid-stride kernel)
//   gemm_qkv:    xb @ w_qkv^T, MFMA 16x16x32, global_load_lds(16B) staging,
//                XCD-swizzled grid 1536 -> bf16 Q/K/V head-major [bh][p][64]
//   attn_fused2: 16x16 pixel tile; K-halo LDS -> dots[25] accumulated over
//                4 chunks of 16 dims (q never fully resident) -> softmax ->
//                V-halo reuses LDS -> o[16] per chunk, stored immediately.
//                Round-5 post-mortem: holding q[64]+dots[25]+o[64] spilled
//                (VGPR=256, 219MB scratch writes, 111us). Chunking caps the
//                live set at ~65 VGPR. #pragma unroll 1 keeps chunks apart.
//   gemm_out:    AO @ w_out^T + b_out -> fp32 out
// ws use: 86 MB of the 256 MiB workspace.

namespace {

typedef short s16x8 __attribute__((ext_vector_type(8)));
typedef unsigned short u16x8 __attribute__((ext_vector_type(8)));
typedef float f32x4 __attribute__((ext_vector_type(4)));

constexpr int kHeads = 8;
constexpr int kN = 4096;          // pixels per image
constexpr float kScale = 0.125f;  // 64^-0.5

__device__ inline float b2f(unsigned short u) {
  return __uint_as_float((unsigned)u << 16);
}
__device__ inline unsigned short f2b(float x) {
  unsigned u = __float_as_uint(x);  // RNE
  return (unsigned short)((u + 0x7fffu + ((u >> 16) & 1u)) >> 16);
}

// async global->LDS, 16 B per lane; LDS dest = wave-uniform base + lane*16
__device__ __forceinline__ void g2l16(const unsigned short* g,
                                      unsigned short* l) {
  __builtin_amdgcn_global_load_lds(
      (const __attribute__((address_space(1))) void*)g,
      (__attribute__((address_space(3))) void*)l, 16, 0, 0);
}

// ---------------- fp32 -> bf16 for all three tensors -------------------------
__global__ __launch_bounds__(256) void cvt_all(
    const float* __restrict__ wq, const float* __restrict__ wo,
    const float* __restrict__ x, unsigned short* __restrict__ wqb,
    unsigned short* __restrict__ wob, unsigned short* __restrict__ xb) {
  const int i = blockIdx.x * 256 + threadIdx.x;  // 0..1179647
  const float* src;
  unsigned short* dst;
  int off;
  if (i < 98304) {
    src = wq; dst = wqb; off = i;
  } else if (i < 131072) {
    src = wo; dst = wob; off = i - 98304;
  } else {
    src = x; dst = xb; off = i - 131072;
  }
  const float4 a = ((const float4*)src)[off * 2];
  const float4 b = ((const float4*)src)[off * 2 + 1];
  u16x8 o;
  o[0] = f2b(a.x); o[1] = f2b(a.y); o[2] = f2b(a.z); o[3] = f2b(a.w);
  o[4] = f2b(b.x); o[5] = f2b(b.y); o[6] = f2b(b.z); o[7] = f2b(b.w);
  *(u16x8*)(dst + (size_t)off * 8) = o;
}

// ---------------- MFMA GEMM core: 128x128 tile, K=512, BK=32 ----------------
__device__ __forceinline__ void mfma_512(const unsigned short* __restrict__ A,
                                         const unsigned short* __restrict__ W,
                                         int m0, int n0, int tid,
                                         unsigned short* As, unsigned short* Bs,
                                         f32x4 (&acc)[4][4]) {
  const int lane = tid & 63;
  const int wv = tid >> 6;
  const int wm = wv & 1, wn = wv >> 1;
  const int rr = lane >> 2;       // row within 16-row group
  const int cc = (lane & 3) * 8;  // k elem offset
#pragma unroll
  for (int i = 0; i < 4; ++i)
#pragma unroll
    for (int j = 0; j < 4; ++j) acc[i][j] = f32x4{0.f, 0.f, 0.f, 0.f};

  for (int k0 = 0; k0 < 512; k0 += 32) {
#pragma unroll
    for (int it = 0; it < 2; ++it) {
      const int grp = wv * 2 + it;  // 0..7
      const int row = grp * 16 + rr;
      g2l16(A + (size_t)(m0 + row) * 512 + k0 + cc, As + grp * 512);
      g2l16(W + (size_t)(n0 + row) * 512 + k0 + cc, Bs + grp * 512);
    }
    __syncthreads();
    s16x8 af[4], bf[4];
#pragma unroll
    for (int i = 0; i < 4; ++i) {
      af[i] = *(const s16x8*)&As[(wm * 64 + i * 16 + (lane & 15)) * 32 +
                                 (lane >> 4) * 8];
      bf[i] = *(const s16x8*)&Bs[(wn * 64 + i * 16 + (lane & 15)) * 32 +
                                 (lane >> 4) * 8];
    }
#pragma unroll
    for (int i = 0; i < 4; ++i)
#pragma unroll
      for (int j = 0; j < 4; ++j)
        acc[i][j] = __builtin_amdgcn_mfma_f32_16x16x32_bf16(af[i], bf[j],
                                                            acc[i][j], 0, 0, 0);
    __syncthreads();
  }
}

// ---------------- QKV projection GEMM, full M=16384 --------------------------
__global__ __launch_bounds__(256, 4) void gemm_qkv(
    const unsigned short* __restrict__ A, const unsigned short* __restrict__ W,
    unsigned short* __restrict__ Qb, unsigned short* __restrict__ Kb,
    unsigned short* __restrict__ Vb) {
  __shared__ unsigned short As[4096], Bs[4096];
  const int tid = threadIdx.x;
  const int id = blockIdx.x;
  const int xcd = id & 7;
  const int j = id >> 3;            // 0..191
  const int by = xcd * 16 + j / 12; // 0..127
  const int bx = j % 12;
  f32x4 acc[4][4];
  mfma_512(A, W, by * 128, bx * 128, tid, As, Bs, acc);

  const int lane = tid & 63;
  const int wv = tid >> 6;
  const int wm = wv & 1, wn = wv >> 1;
  const int cn = bx * 128 + wn * 64;  // 64-aligned => head/qkv wave-uniform
  unsigned short* dst = (cn < 512) ? Qb : (cn < 1024 ? Kb : Vb);
  const int head = (cn >> 6) & 7;
  const int colb = lane & 15;
#pragma unroll
  for (int mi = 0; mi < 4; ++mi) {
#pragma unroll
    for (int r = 0; r < 4; ++r) {
      const int m = by * 128 + wm * 64 + mi * 16 + (lane >> 4) * 4 + r;
      const int b = m >> 12;
      const int p = m & 4095;
      unsigned short* o =
          dst + ((size_t)(b * kHeads + head) * kN + p) * 64 + colb;
#pragma unroll
      for (int ni = 0; ni < 4; ++ni) o[ni * 16] = f2b(acc[mi][ni][r]);
    }
  }
}

// ---------------- out-projection GEMM ----------------------------------------
__global__ __launch_bounds__(256, 4) void gemm_out(
    const unsigned short* __restrict__ A, const unsigned short* __restrict__ W,
    const float* __restrict__ bias, float* __restrict__ out) {
  __shared__ unsigned short As[4096], Bs[4096];
  const int tid = threadIdx.x;
  const int id = blockIdx.x;
  const int xcd = id & 7;
  const int j = id >> 3;               // 0..63
  const int by = xcd * 16 + (j >> 2);  // 0..127
  const int bx = j & 3;
  f32x4 acc[4][4];
  mfma_512(A, W, by * 128, bx * 128, tid, As, Bs, acc);

  const int lane = tid & 63;
  const int wv = tid >> 6;
  const int wm = wv & 1, wn = wv >> 1;
  float bvr[4];
#pragma unroll
  for (int ni = 0; ni < 4; ++ni)
    bvr[ni] = bias[bx * 128 + wn * 64 + ni * 16 + (lane & 15)];
#pragma unroll
  for (int mi = 0; mi < 4; ++mi) {
#pragma unroll
    for (int r = 0; r < 4; ++r) {
      const int m = by * 128 + wm * 64 + mi * 16 + (lane >> 4) * 4 + r;
      float* o = out + (size_t)m * 512 + bx * 128 + wn * 64 + (lane & 15);
#pragma unroll
      for (int ni = 0; ni < 4; ++ni) o[ni * 16] = acc[mi][ni][r] + bvr[ni];
    }
  }
}

// ---------------- fused local attention, register-chunked --------------------
__device__ __forceinline__ void load_halo(const unsigned short* __restrict__ T,
                                          size_t base, int ty0, int tx0,
                                          int tid, unsigned short* H) {
  for (int i = tid; i < 3200; i += 256) {
    const int r = i >> 3, c = i & 7;
    const int gy = ty0 - 2 + r / 20;
    const int gx = tx0 - 2 + r % 20;
    u16x8 v = {};
    if ((unsigned)gy < 64u && (unsigned)gx < 64u)
      v = *(const u16x8*)(T + (base + gy * 64 + gx) * 64 + c * 8);
    *(u16x8*)&H[r * 72 + c * 8] = v;
  }
}

__global__ __launch_bounds__(256) void attn_fused2(
    const unsigned short* __restrict__ Q, const unsigned short* __restrict__ K,
    const unsigned short* __restrict__ V, unsigned short* __restrict__ AO) {
  __shared__ unsigned short H[400 * 72];  // 57.6 KB -> 2 blocks/CU
  const int tid = threadIdx.x;
  const int bh = blockIdx.y;
  const int tile = blockIdx.x;
  const int ty0 = (tile >> 2) * 16, tx0 = (tile & 3) * 16;
  const size_t base = (size_t)bh * kN;
  const int pyl = tid >> 4, pxl = tid & 15;
  const int p = (ty0 + pyl) * 64 + tx0 + pxl;

  // ---- phase 1: K halo, dots over 4 chunks of 16 dims ----
  load_halo(K, base, ty0, tx0, tid, H);
  __syncthreads();

  float dots[25];
#pragma unroll
  for (int f = 0; f < 25; ++f) dots[f] = 0.f;

  const unsigned short* qp = Q + (base + p) * 64;
#pragma unroll 1
  for (int c = 0; c < 4; ++c) {
    float qv[16];
    {
      const u16x8 a = *(const u16x8*)(qp + c * 16);
      const u16x8 b = *(const u16x8*)(qp + c * 16 + 8);
#pragma unroll
      for (int j = 0; j < 8; ++j) {
        qv[j] = b2f(a[j]);
        qv[8 + j] = b2f(b[j]);
      }
    }
#pragma unroll
    for (int fy = 0; fy < 5; ++fy) {
#pragma unroll
      for (int fx = 0; fx < 5; ++fx) {
        const unsigned short* kr =
            &H[((pyl + fy) * 20 + pxl + fx) * 72 + c * 16];
        const u16x8 a = *(const u16x8*)kr;
        const u16x8 b = *(const u16x8*)(kr + 8);
        float d = dots[fy * 5 + fx];
#pragma unroll
        for (int j = 0; j < 8; ++j) d = fmaf(qv[j], b2f(a[j]), d);
#pragma unroll
        for (int j = 0; j < 8; ++j) d = fmaf(qv[8 + j], b2f(b[j]), d);
        dots[fy * 5 + fx] = d;
      }
    }
  }

  float mx = -1e30f;
#pragma unroll
  for (int f = 0; f < 25; ++f) {
    dots[f] *= kScale;
    mx = fmaxf(mx, dots[f]);
  }
  float sum = 0.f;
#pragma unroll
  for (int f = 0; f < 25; ++f) {
    dots[f] = __expf(dots[f] - mx);
    sum += dots[f];
  }
  const float inv = 1.f / sum;
#pragma unroll
  for (int f = 0; f < 25; ++f) dots[f] *= inv;

  // ---- phase 2: V halo reuses H; o in 4 chunks of 16 dims ----
  __syncthreads();  // everyone done reading K halo
  load_halo(V, base, ty0, tx0, tid, H);
  __syncthreads();

  const int b = bh >> 3, h = bh & 7;
  unsigned short* op = AO + ((size_t)(b * kN + p)) * 512 + h * 64;
#pragma unroll 1
  for (int c = 0; c < 4; ++c) {
    float o[16];
#pragma unroll
    for (int j = 0; j < 16; ++j) o[j] = 0.f;
#pragma unroll
    for (int fy = 0; fy < 5; ++fy) {
#pragma unroll
      for (int fx = 0; fx < 5; ++fx) {
        const unsigned short* vr =
            &H[((pyl + fy) * 20 + pxl + fx) * 72 + c * 16];
        const u16x8 a = *(const u16x8*)vr;
        const u16x8 b2 = *(const u16x8*)(vr + 8);
        const float wf = dots[fy * 5 + fx];
#pragma unroll
        for (int j = 0; j < 8; ++j) o[j] = fmaf(wf, b2f(a[j]), o[j]);
#pragma unroll
        for (int j = 0; j < 8; ++j) o[8 + j] = fmaf(wf, b2f(b2[j]), o[8 + j]);
      }
    }
    u16x8 pa, pb;
#pragma unroll
    for (int j = 0; j < 8; ++j) {
      pa[j] = f2b(o[j]);
      pb[j] = f2b(o[8 + j]);
    }
    *(u16x8*)(op + c * 16) = pa;
    *(u16x8*)(op + c * 16 + 8) = pb;
  }
}

}  // namespace

extern "C" void kernel_launch(void* const* d_in, const int* in_sizes, int n_in,
                              void* d_out, int out_size, void* d_ws,
                              size_t ws_size, hipStream_t stream) {
  (void)in_sizes; (void)n_in; (void)out_size; (void)ws_size;
  const float* x = (const float*)d_in[0];      // [4,4096,512]
  const float* w_qkv = (const float*)d_in[1];  // [1536,512]
  const float* w_out = (const float*)d_in[2];  // [512,512]
  const float* b_out = (const float*)d_in[3];  // [512]
  float* out = (float*)d_out;                  // [4,4096,512] fp32

  unsigned short* ws0 = (unsigned short*)d_ws;
  unsigned short* wqkvb = ws0;              //   786,432
  unsigned short* woutb = ws0 + 786432;     //   262,144
  unsigned short* xb = ws0 + 1048576;       // 8,388,608
  unsigned short* Qb = ws0 + 9437184;       // 8,388,608
  unsigned short* Kb = ws0 + 17825792;      // 8,388,608
  unsigned short* Vb = ws0 + 26214400;      // 8,388,608
  unsigned short* AO = ws0 + 34603008;      // 8,388,608 -> 86 MB total

  cvt_all<<<4608, 256, 0, stream>>>(w_qkv, w_out, x, wqkvb, woutb, xb);
  gemm_qkv<<<1536, 256, 0, stream>>>(xb, wqkvb, Qb, Kb, Vb);
  attn_fused2<<<dim3(16, 32), 256, 0, stream>>>(Qb, Kb, Vb, AO);
  gemm_out<<<512, 256, 0, stream>>>(AO, woutb, b_out, out);
}